// Round 3
// baseline (271.883 us; speedup 1.0000x reference)
//
#include <hip/hip_runtime.h>
#include <hip/hip_bf16.h>
#include <math.h>

#define BB 32
#define SS 4096
#define HH 256

typedef __bf16 bf16x8 __attribute__((ext_vector_type(8)));
typedef float f32x4 __attribute__((ext_vector_type(4)));

#define GLOBAL_AS __attribute__((address_space(1)))
#define LDS_AS    __attribute__((address_space(3)))

__device__ inline bf16x8 cvt8(const float4& x, const float4& y) {
    union { __hip_bfloat162 p[4]; bf16x8 v; } u;
    u.p[0] = __float22bfloat162_rn(make_float2(x.x, x.y));
    u.p[1] = __float22bfloat162_rn(make_float2(x.z, x.w));
    u.p[2] = __float22bfloat162_rn(make_float2(y.x, y.y));
    u.p[3] = __float22bfloat162_rn(make_float2(y.z, y.w));
    return u.v;
}

// tanh(x) = 1 - 2/(e^{2x}+1). Clamp-free: exp2 overflow -> +inf -> rcp=0 -> 1;
// underflow -> 0 -> 1-2 = -1. ~5 VALU ops.
__device__ inline float fast_tanh(float x) {
    float e = __builtin_amdgcn_exp2f(x * 2.8853900817779268f);  // 2*log2(e)
    return 1.f - 2.f * __builtin_amdgcn_rcpf(e + 1.f);
}

// ---------------------------------------------------------------------------
// Prep (unchanged): blocks 0..255 swizzle W2 -> bf16 MFMA-B order;
// blocks 256..287: qq[b][h] = hidden[b]@W1[:,h] + W1_b[h] + W2_b[h];
// block 288: M = sum_h |V_w[h]|  (upper bound on V.tanh; V_b cancels).
// w2sw[((kc*16+nt)*64+lane)*8+j] = W2[kc*32+(lane>>4)*8+j][nt*16+(lane&15)]
// ---------------------------------------------------------------------------
__global__ void prep_kernel(const float* __restrict__ W2_w,
                            ushort* __restrict__ w2sw,
                            const float* __restrict__ hidden,
                            const float* __restrict__ W1_w,
                            const float* __restrict__ W1_b,
                            const float* __restrict__ W2_b,
                            const float* __restrict__ V_w,
                            float* __restrict__ qq,
                            float* __restrict__ Mout) {
    __shared__ float red[HH];
    const int t = threadIdx.x;
    if (blockIdx.x < 256) {
        const int i = blockIdx.x * 256 + t;
        const int j    = i & 7;
        const int lane = (i >> 3) & 63;
        const int nt   = (i >> 9) & 15;
        const int kc   = i >> 13;
        const int k = kc * 32 + ((lane >> 4) & 3) * 8 + j;
        const int n = nt * 16 + (lane & 15);
        __hip_bfloat16 h = __float2bfloat16(W2_w[k * HH + n]);
        w2sw[i] = *(ushort*)&h;
    } else if (blockIdx.x < 256 + BB) {
        const int b = blockIdx.x - 256;
        red[t] = hidden[b * HH + t];
        __syncthreads();
        float acc = 0.f;
#pragma unroll 16
        for (int k = 0; k < HH; ++k)
            acc = fmaf(red[k], W1_w[k * HH + t], acc);
        qq[b * HH + t] = acc + W1_b[t] + W2_b[t];
    } else {
        red[t] = fabsf(V_w[t]);
        __syncthreads();
        for (int off = 128; off > 0; off >>= 1) {
            if (t < off) red[t] += red[t + off];
            __syncthreads();
        }
        if (t == 0) Mout[0] = red[0];
    }
}

// ---------------------------------------------------------------------------
// Fused score + partial-context v3: grid (SS/512, BB), block 1024 = 16 waves
// as 8 m-groups x 2 n-halves, 1 block/CU. W2 (128 KB bf16 swizzled) resident
// in LDS for the whole block. Wave tile = 32 rows x 128 cols (acc[2][8]):
// each B ds_read_b128 feeds TWO MFMAs -> LDS traffic halved vs 16-row strips
// (2 MB/CU, ~10 us). 2 passes x 256 rows. Per pass: barrier-free K-loop
// (A 1-deep reg prefetch from HBM, B from resident LDS), ONE barrier for the
// n-half score combine (sc double-buffered by pass parity), then next-pass A
// loads are issued BEFORE the ctx phase so ctx's L2 reads hide the next
// K-loop's HBM latency. Ctx partial lives in registers across both passes.
// ---------------------------------------------------------------------------
__global__ __launch_bounds__(1024, 4)
void score_ctx_kernel(const float* __restrict__ enc,
                      const ushort* __restrict__ w2sw,
                      const float* __restrict__ qq,
                      const float* __restrict__ V_w,
                      const float* __restrict__ Mptr,
                      float* __restrict__ wtilde,
                      float* __restrict__ part) {
    extern __shared__ char smem[];
    ushort* w2buf = (ushort*)smem;               // 131072 B: full swizzled W2
    float*  sc    = (float*)(smem + 131072);     // [2 par][2 nw][256] = 8 KB
    float*  ctxl  = (float*)(smem + 139264);     // [16][256] = 16 KB

    const int t    = threadIdx.x;
    const int b    = blockIdx.y;
    const int cx   = blockIdx.x;
    const int wid  = t >> 6;
    const int lane = t & 63;
    const int l15  = lane & 15;
    const int quad = lane >> 4;
    const int mw   = wid & 7;
    const int nw   = wid >> 3;

    // Stage all of W2 into LDS (linear; 1024 thr x 16B = 16KB/sweep, 8 sweeps)
    {
        const char* gsrc = (const char*)w2sw + t * 16;
        char* ldst = smem + wid * 1024;
#pragma unroll
        for (int i = 0; i < 8; ++i)
            __builtin_amdgcn_global_load_lds(
                (const GLOBAL_AS void*)(gsrc + i * 16384),
                (LDS_AS void*)(ldst + i * 16384), 16, 0, 0);
    }

    const float Mv = Mptr[0];
    const size_t encb = (size_t)b * SS;
    float4 cacc = make_float4(0.f, 0.f, 0.f, 0.f);

    // Pass-0 A pointers + first loads (independent of LDS -> before barrier).
    const float* rowp0 =
        enc + (encb + cx * 512 + mw * 32 + l15) * HH + (quad << 3);
    const float* rowp1 = rowp0 + (size_t)16 * HH;
    float4 ax0 = *(const float4*)rowp0, ay0 = *(const float4*)(rowp0 + 4);
    float4 ax1 = *(const float4*)rowp1, ay1 = *(const float4*)(rowp1 + 4);

    __syncthreads();   // W2 resident

#pragma unroll
    for (int p = 0; p < 2; ++p) {
        const int par     = p & 1;
        const int rowbase = mw * 32;                       // within-pass
        const int srow    = cx * 512 + p * 256 + rowbase;  // global row base

        f32x4 acc[2][8];
#pragma unroll
        for (int mt = 0; mt < 2; ++mt)
#pragma unroll
            for (int nt = 0; nt < 8; ++nt) acc[mt][nt] = (f32x4)0.f;

#pragma unroll
        for (int kc = 0; kc < 8; ++kc) {
            float4 n0x, n0y, n1x, n1y;
            if (kc < 7) {   // 1-deep prefetch of next K-chunk
                const int o = (kc + 1) * 32;
                n0x = *(const float4*)(rowp0 + o);
                n0y = *(const float4*)(rowp0 + o + 4);
                n1x = *(const float4*)(rowp1 + o);
                n1y = *(const float4*)(rowp1 + o + 4);
            }
            const bf16x8 af0 = cvt8(ax0, ay0);
            const bf16x8 af1 = cvt8(ax1, ay1);
#pragma unroll
            for (int nt = 0; nt < 8; ++nt) {
                const bf16x8 bfr = *(const bf16x8*)
                    &w2buf[((kc * 16 + nw * 8 + nt) * 64 + lane) * 8];
                acc[0][nt] = __builtin_amdgcn_mfma_f32_16x16x32_bf16(
                    af0, bfr, acc[0][nt], 0, 0, 0);
                acc[1][nt] = __builtin_amdgcn_mfma_f32_16x16x32_bf16(
                    af1, bfr, acc[1][nt], 0, 0, 0);
            }
            if (kc < 7) { ax0 = n0x; ay0 = n0y; ax1 = n1x; ay1 = n1y; }
        }

        // Scores over this wave's n-half. C layout: col=l15, row=quad*4+r.
        float p0[2][4] = {{0.f, 0.f, 0.f, 0.f}, {0.f, 0.f, 0.f, 0.f}};
#pragma unroll
        for (int nt = 0; nt < 8; ++nt) {
            const int n = nw * 128 + nt * 16 + l15;
            const float qn = qq[b * HH + n];   // L1-hot after first use
            const float vn = V_w[n];
#pragma unroll
            for (int mt = 0; mt < 2; ++mt)
#pragma unroll
                for (int r = 0; r < 4; ++r)
                    p0[mt][r] =
                        fmaf(vn, fast_tanh(qn + acc[mt][nt][r]), p0[mt][r]);
        }
#pragma unroll
        for (int off = 1; off < 16; off <<= 1)
#pragma unroll
            for (int mt = 0; mt < 2; ++mt)
#pragma unroll
                for (int r = 0; r < 4; ++r)
                    p0[mt][r] += __shfl_xor(p0[mt][r], off);

        if (l15 == 0) {
#pragma unroll
            for (int mt = 0; mt < 2; ++mt)
                *(float4*)&sc[(par * 2 + nw) * 256 + rowbase + mt * 16 +
                              quad * 4] =
                    make_float4(p0[mt][0], p0[mt][1], p0[mt][2], p0[mt][3]);
        }
        __syncthreads();

        // Issue next-pass A loads NOW: ctx phase below hides their latency.
        if (p == 0) {
            rowp0 = enc + (encb + cx * 512 + 256 + mw * 32 + l15) * HH +
                    (quad << 3);
            rowp1 = rowp0 + (size_t)16 * HH;
            ax0 = *(const float4*)rowp0; ay0 = *(const float4*)(rowp0 + 4);
            ax1 = *(const float4*)rowp1; ay1 = *(const float4*)(rowp1 + 4);
        }

        // wtilde write (one wave set per m-group).
        if (nw == 0 && l15 == 0) {
#pragma unroll
            for (int mt = 0; mt < 2; ++mt) {
                const float* o =
                    &sc[(par * 2 + 1) * 256 + rowbase + mt * 16 + quad * 4];
                *(float4*)&wtilde[encb + srow + mt * 16 + quad * 4] =
                    make_float4(__expf(p0[mt][0] + o[0] - Mv),
                                __expf(p0[mt][1] + o[1] - Mv),
                                __expf(p0[mt][2] + o[2] - Mv),
                                __expf(p0[mt][3] + o[3] - Mv));
            }
        }

        // Ctx partial: this wave takes 16 of its 32 rows (nw picks the half;
        // those rows were this wave's own A tile -> L1/L2-hot).
        const float* ep = enc + (encb + srow + nw * 16) * HH + (lane << 2);
        const float* sA = &sc[(par * 2 + 0) * 256 + rowbase + nw * 16];
        const float* sB = &sc[(par * 2 + 1) * 256 + rowbase + nw * 16];
#pragma unroll
        for (int j = 0; j < 16; ++j) {
            const float w = __expf(sA[j] + sB[j] - Mv);   // LDS broadcast
            const float4 e = *(const float4*)(ep + (size_t)j * HH);
            cacc.x = fmaf(w, e.x, cacc.x);
            cacc.y = fmaf(w, e.y, cacc.y);
            cacc.z = fmaf(w, e.z, cacc.z);
            cacc.w = fmaf(w, e.w, cacc.w);
        }
    }

    // Block-level context reduce: 16 waves -> one partial per block.
    *(float4*)&ctxl[wid * HH + (lane << 2)] = cacc;
    __syncthreads();
    if (t < HH) {
        float s = 0.f;
#pragma unroll
        for (int w = 0; w < 16; ++w) s += ctxl[w * HH + t];
        part[((size_t)(b * 8 + cx)) * HH + t] = s;
    }
}

// ---------------------------------------------------------------------------
// Finish: grid (BB), block 256. l = sum_s wtilde; weights = wtilde/l;
// ctx = (sum_c part)/l.  (8 partials per b.)
// ---------------------------------------------------------------------------
__global__ __launch_bounds__(256)
void finish_kernel(const float* __restrict__ wtilde,
                   const float* __restrict__ part,
                   float* __restrict__ weights_out,
                   float* __restrict__ ctx_out) {
    __shared__ float red[256];
    __shared__ float linv_s;
    const int b = blockIdx.x;
    const int t = threadIdx.x;

    const float4* wt4 = (const float4*)(wtilde + (size_t)b * SS);
    float4 vals[4];
    float l = 0.f;
#pragma unroll
    for (int i = 0; i < 4; ++i) {
        vals[i] = wt4[i * 256 + t];
        l += vals[i].x + vals[i].y + vals[i].z + vals[i].w;
    }
    red[t] = l;
    __syncthreads();
    for (int off = 128; off > 0; off >>= 1) {
        if (t < off) red[t] += red[t + off];
        __syncthreads();
    }
    if (t == 0) linv_s = 1.f / red[0];
    __syncthreads();
    const float linv = linv_s;

    float4* wo4 = (float4*)(weights_out + (size_t)b * SS);
#pragma unroll
    for (int i = 0; i < 4; ++i) {
        const float4 v = vals[i];
        wo4[i * 256 + t] =
            make_float4(v.x * linv, v.y * linv, v.z * linv, v.w * linv);
    }

    float a = 0.f;
#pragma unroll
    for (int c = 0; c < 8; ++c)
        a += part[((size_t)(b * 8 + c)) * HH + t];
    ctx_out[b * HH + t] = a * linv;
}

// ---------------------------------------------------------------------------
extern "C" void kernel_launch(void* const* d_in, const int* in_sizes, int n_in,
                              void* d_out, int out_size, void* d_ws, size_t ws_size,
                              hipStream_t stream) {
    const float* hidden = (const float*)d_in[0];
    const float* enc    = (const float*)d_in[1];
    const float* W1_w   = (const float*)d_in[2];
    const float* W1_b   = (const float*)d_in[3];
    const float* W2_w   = (const float*)d_in[4];
    const float* W2_b   = (const float*)d_in[5];
    const float* V_w    = (const float*)d_in[6];
    const float* V_b    = (const float*)d_in[7];
    (void)V_b;  // cancels in the shifted softmax

    float* out_weights = (float*)d_out;                 // B*S
    float* out_ctx     = (float*)d_out + BB * SS;       // B*H

    float* ws      = (float*)d_ws;
    float* ws_qq   = ws;                                 // 8192
    float* ws_wt   = ws_qq + BB * HH;                    // 131072
    float* ws_part = ws_wt + BB * SS;                    // (region reserved)
    float* ws_M    = ws_part + BB * 64 * HH;             // 1
    ushort* ws_w2  = (ushort*)(ws_M + 4);                // 65536 bf16

    static bool attr_done = false;
    if (!attr_done) {
        hipFuncSetAttribute(reinterpret_cast<const void*>(score_ctx_kernel),
                            hipFuncAttributeMaxDynamicSharedMemorySize,
                            155648);
        attr_done = true;
    }

    prep_kernel<<<dim3(256 + BB + 1), dim3(256), 0, stream>>>(
        W2_w, ws_w2, hidden, W1_w, W1_b, W2_b, V_w, ws_qq, ws_M);
    score_ctx_kernel<<<dim3(SS / 512, BB), dim3(1024), 155648, stream>>>(
        enc, ws_w2, ws_qq, V_w, ws_M, ws_wt, ws_part);
    finish_kernel<<<dim3(BB), dim3(256), 0, stream>>>(
        ws_wt, ws_part, out_weights, out_ctx);
}

// Round 4
// 252.408 us; speedup vs baseline: 1.0772x; 1.0772x over previous
//
#include <hip/hip_runtime.h>
#include <hip/hip_bf16.h>
#include <math.h>

#define BB 32
#define SS 4096
#define HH 256

typedef __bf16 bf16x8 __attribute__((ext_vector_type(8)));
typedef float f32x4 __attribute__((ext_vector_type(4)));

#define GLOBAL_AS __attribute__((address_space(1)))
#define LDS_AS    __attribute__((address_space(3)))

__device__ inline bf16x8 cvt8(const float4& x, const float4& y) {
    union { __hip_bfloat162 p[4]; bf16x8 v; } u;
    u.p[0] = __float22bfloat162_rn(make_float2(x.x, x.y));
    u.p[1] = __float22bfloat162_rn(make_float2(x.z, x.w));
    u.p[2] = __float22bfloat162_rn(make_float2(y.x, y.y));
    u.p[3] = __float22bfloat162_rn(make_float2(y.z, y.w));
    return u.v;
}

// tanh(x) = 1 - 2/(e^{2x}+1). Clamp-free: exp2 overflow -> +inf -> rcp=0 -> 1;
// underflow -> 0 -> 1-2 = -1. ~5 VALU ops.
__device__ inline float fast_tanh(float x) {
    float e = __builtin_amdgcn_exp2f(x * 2.8853900817779268f);  // 2*log2(e)
    return 1.f - 2.f * __builtin_amdgcn_rcpf(e + 1.f);
}

// ---------------------------------------------------------------------------
// Prep (unchanged): blocks 0..255 swizzle W2 -> bf16 MFMA-B order;
// blocks 256..287: qq[b][h] = hidden[b]@W1[:,h] + W1_b[h] + W2_b[h];
// block 288: M = sum_h |V_w[h]|  (upper bound on V.tanh; V_b cancels).
// w2sw[((kc*16+nt)*64+lane)*8+j] = W2[kc*32+(lane>>4)*8+j][nt*16+(lane&15)]
// ---------------------------------------------------------------------------
__global__ void prep_kernel(const float* __restrict__ W2_w,
                            ushort* __restrict__ w2sw,
                            const float* __restrict__ hidden,
                            const float* __restrict__ W1_w,
                            const float* __restrict__ W1_b,
                            const float* __restrict__ W2_b,
                            const float* __restrict__ V_w,
                            float* __restrict__ qq,
                            float* __restrict__ Mout) {
    __shared__ float red[HH];
    const int t = threadIdx.x;
    if (blockIdx.x < 256) {
        const int i = blockIdx.x * 256 + t;
        const int j    = i & 7;
        const int lane = (i >> 3) & 63;
        const int nt   = (i >> 9) & 15;
        const int kc   = i >> 13;
        const int k = kc * 32 + ((lane >> 4) & 3) * 8 + j;
        const int n = nt * 16 + (lane & 15);
        __hip_bfloat16 h = __float2bfloat16(W2_w[k * HH + n]);
        w2sw[i] = *(ushort*)&h;
    } else if (blockIdx.x < 256 + BB) {
        const int b = blockIdx.x - 256;
        red[t] = hidden[b * HH + t];
        __syncthreads();
        float acc = 0.f;
#pragma unroll 16
        for (int k = 0; k < HH; ++k)
            acc = fmaf(red[k], W1_w[k * HH + t], acc);
        qq[b * HH + t] = acc + W1_b[t] + W2_b[t];
    } else {
        red[t] = fabsf(V_w[t]);
        __syncthreads();
        for (int off = 128; off > 0; off >>= 1) {
            if (t < off) red[t] += red[t + off];
            __syncthreads();
        }
        if (t == 0) Mout[0] = red[0];
    }
}

// ---------------------------------------------------------------------------
// Fused score + partial-context v4: grid (SS/512, BB), block 1024 = 16 waves
// as 8 m-groups x 2 n-halves, 1 block/CU. W2 (128 KB bf16 swizzled) resident
// in LDS. Wave tile 32 rows x 128 cols (acc[2][8] -> AGPR, 64 regs; each B
// ds_read_b128 feeds two MFMAs). REGISTER DISCIPLINE (round-3 spilled 60
// dwords/thread): A pipeline is an IN-PLACE ROTATE — cvt kills ax/ay, then
// the same regs are reloaded with the next kc (next-pass base at kc==7), so
// the A buffer never doubles; '#pragma unroll 1' on kc- and p-loops stops
// the compiler from rebuilding deep buffers; p0 dies at the sc write
// (wtilde is recomputed from sc, same reads the ctx loop does). Live set
// ~114 regs < 128 cap at __launch_bounds__(1024,4).
// ---------------------------------------------------------------------------
__global__ __launch_bounds__(1024, 4)
void score_ctx_kernel(const float* __restrict__ enc,
                      const ushort* __restrict__ w2sw,
                      const float* __restrict__ qq,
                      const float* __restrict__ V_w,
                      const float* __restrict__ Mptr,
                      float* __restrict__ wtilde,
                      float* __restrict__ part) {
    extern __shared__ char smem[];
    ushort* w2buf = (ushort*)smem;               // 131072 B: full swizzled W2
    float*  sc    = (float*)(smem + 131072);     // [2 par][2 nw][256] = 4 KB
    float*  ctxl  = (float*)(smem + 135168);     // [16][256] = 16 KB

    const int t    = threadIdx.x;
    const int b    = blockIdx.y;
    const int cx   = blockIdx.x;
    const int wid  = t >> 6;
    const int lane = t & 63;
    const int l15  = lane & 15;
    const int quad = lane >> 4;
    const int mw   = wid & 7;
    const int nw   = wid >> 3;

    // Stage all of W2 into LDS (linear; 1024 thr x 16B = 16KB/sweep, 8 sweeps)
    {
        const char* gsrc = (const char*)w2sw + t * 16;
        char* ldst = smem + wid * 1024;
#pragma unroll
        for (int i = 0; i < 8; ++i)
            __builtin_amdgcn_global_load_lds(
                (const GLOBAL_AS void*)(gsrc + i * 16384),
                (LDS_AS void*)(ldst + i * 16384), 16, 0, 0);
    }

    const float Mv = Mptr[0];
    const size_t encb = (size_t)b * SS;
    float4 cacc = make_float4(0.f, 0.f, 0.f, 0.f);

    // Pass-0 A base (rows mw*32 + {l15, 16+l15}), kc=0 loads before barrier.
    const float* rowp0 =
        enc + (encb + cx * 512 + mw * 32 + l15) * HH + (quad << 3);
    float4 ax0 = *(const float4*)rowp0;
    float4 ay0 = *(const float4*)(rowp0 + 4);
    float4 ax1 = *(const float4*)(rowp0 + 16 * HH);
    float4 ay1 = *(const float4*)(rowp0 + 16 * HH + 4);

    __syncthreads();   // W2 resident

#pragma unroll 1
    for (int p = 0; p < 2; ++p) {
        const int par     = p;
        const int rowbase = mw * 32;
        const int srow    = cx * 512 + p * 256 + rowbase;

        f32x4 acc[2][8];
#pragma unroll
        for (int mt = 0; mt < 2; ++mt)
#pragma unroll
            for (int nt = 0; nt < 8; ++nt) acc[mt][nt] = (f32x4)0.f;

#pragma unroll 1
        for (int kc = 0; kc < 8; ++kc) {
            const bf16x8 af0 = cvt8(ax0, ay0);   // ax/ay die here
            const bf16x8 af1 = cvt8(ax1, ay1);
            // In-place rotate: reload same regs with next kc (next pass's
            // kc=0 at kc==7; last pass re-reads own row 0 — harmless, keeps
            // the address in bounds).
            {
                const int o = (kc < 7) ? (kc + 1) * 32
                                       : ((p == 0) ? 256 * HH : 0);
                ax0 = *(const float4*)(rowp0 + o);
                ay0 = *(const float4*)(rowp0 + o + 4);
                ax1 = *(const float4*)(rowp0 + o + 16 * HH);
                ay1 = *(const float4*)(rowp0 + o + 16 * HH + 4);
            }
            const ushort* wb = &w2buf[((kc * 16 + nw * 8) * 64 + lane) * 8];
#pragma unroll
            for (int nt = 0; nt < 8; ++nt) {
                const bf16x8 bfr = *(const bf16x8*)(wb + nt * 512);
                acc[0][nt] = __builtin_amdgcn_mfma_f32_16x16x32_bf16(
                    af0, bfr, acc[0][nt], 0, 0, 0);
                acc[1][nt] = __builtin_amdgcn_mfma_f32_16x16x32_bf16(
                    af1, bfr, acc[1][nt], 0, 0, 0);
            }
        }
        if (p == 0) rowp0 += 256 * HH;   // pass-1 base (loads already issued)

        // Scores over this wave's n-half. C layout: col=l15, row=quad*4+r.
        {
            float p0[2][4] = {{0.f, 0.f, 0.f, 0.f}, {0.f, 0.f, 0.f, 0.f}};
#pragma unroll
            for (int nt = 0; nt < 8; ++nt) {
                const int n = nw * 128 + nt * 16 + l15;
                const float qn = qq[b * HH + n];
                const float vn = V_w[n];
#pragma unroll
                for (int mt = 0; mt < 2; ++mt)
#pragma unroll
                    for (int r = 0; r < 4; ++r)
                        p0[mt][r] = fmaf(
                            vn, fast_tanh(qn + acc[mt][nt][r]), p0[mt][r]);
            }
#pragma unroll
            for (int off = 1; off < 16; off <<= 1)
#pragma unroll
                for (int mt = 0; mt < 2; ++mt)
#pragma unroll
                    for (int r = 0; r < 4; ++r)
                        p0[mt][r] += __shfl_xor(p0[mt][r], off);

            if (l15 == 0) {
#pragma unroll
                for (int mt = 0; mt < 2; ++mt)
                    *(float4*)&sc[(par * 2 + nw) * 256 + rowbase + mt * 16 +
                                  quad * 4] =
                        make_float4(p0[mt][0], p0[mt][1], p0[mt][2],
                                    p0[mt][3]);
            }
        }   // p0 dead before the barrier
        __syncthreads();

        // wtilde: recompute from sc (both halves visible after barrier).
        if (nw == 0 && l15 == 0) {
#pragma unroll
            for (int mt = 0; mt < 2; ++mt) {
                const int rb = rowbase + mt * 16 + quad * 4;
                const float4 u = *(const float4*)&sc[(par * 2 + 0) * 256 + rb];
                const float4 v = *(const float4*)&sc[(par * 2 + 1) * 256 + rb];
                *(float4*)&wtilde[encb + srow + mt * 16 + quad * 4] =
                    make_float4(__expf(u.x + v.x - Mv), __expf(u.y + v.y - Mv),
                                __expf(u.z + v.z - Mv), __expf(u.w + v.w - Mv));
            }
        }

        // Ctx partial: this wave takes 16 of its 32 rows (nw picks the half;
        // rows are this wave's own A tile -> L1/L2-hot).
        const float* ep = enc + (encb + srow + nw * 16) * HH + (lane << 2);
        const float* sA = &sc[(par * 2 + 0) * 256 + rowbase + nw * 16];
        const float* sB = &sc[(par * 2 + 1) * 256 + rowbase + nw * 16];
#pragma unroll
        for (int j = 0; j < 16; ++j) {
            const float w = __expf(sA[j] + sB[j] - Mv);   // LDS broadcast
            const float4 e = *(const float4*)(ep + (size_t)j * HH);
            cacc.x = fmaf(w, e.x, cacc.x);
            cacc.y = fmaf(w, e.y, cacc.y);
            cacc.z = fmaf(w, e.z, cacc.z);
            cacc.w = fmaf(w, e.w, cacc.w);
        }
    }

    // Block-level context reduce: 16 waves -> one partial per block.
    *(float4*)&ctxl[wid * HH + (lane << 2)] = cacc;
    __syncthreads();
    if (t < HH) {
        float s = 0.f;
#pragma unroll
        for (int w = 0; w < 16; ++w) s += ctxl[w * HH + t];
        part[((size_t)(b * 8 + cx)) * HH + t] = s;
    }
}

// ---------------------------------------------------------------------------
// Finish: grid (BB), block 256. l = sum_s wtilde; weights = wtilde/l;
// ctx = (sum_c part)/l.  (8 partials per b.)
// ---------------------------------------------------------------------------
__global__ __launch_bounds__(256)
void finish_kernel(const float* __restrict__ wtilde,
                   const float* __restrict__ part,
                   float* __restrict__ weights_out,
                   float* __restrict__ ctx_out) {
    __shared__ float red[256];
    __shared__ float linv_s;
    const int b = blockIdx.x;
    const int t = threadIdx.x;

    const float4* wt4 = (const float4*)(wtilde + (size_t)b * SS);
    float4 vals[4];
    float l = 0.f;
#pragma unroll
    for (int i = 0; i < 4; ++i) {
        vals[i] = wt4[i * 256 + t];
        l += vals[i].x + vals[i].y + vals[i].z + vals[i].w;
    }
    red[t] = l;
    __syncthreads();
    for (int off = 128; off > 0; off >>= 1) {
        if (t < off) red[t] += red[t + off];
        __syncthreads();
    }
    if (t == 0) linv_s = 1.f / red[0];
    __syncthreads();
    const float linv = linv_s;

    float4* wo4 = (float4*)(weights_out + (size_t)b * SS);
#pragma unroll
    for (int i = 0; i < 4; ++i) {
        const float4 v = vals[i];
        wo4[i * 256 + t] =
            make_float4(v.x * linv, v.y * linv, v.z * linv, v.w * linv);
    }

    float a = 0.f;
#pragma unroll
    for (int c = 0; c < 8; ++c)
        a += part[((size_t)(b * 8 + c)) * HH + t];
    ctx_out[b * HH + t] = a * linv;
}

// ---------------------------------------------------------------------------
extern "C" void kernel_launch(void* const* d_in, const int* in_sizes, int n_in,
                              void* d_out, int out_size, void* d_ws, size_t ws_size,
                              hipStream_t stream) {
    const float* hidden = (const float*)d_in[0];
    const float* enc    = (const float*)d_in[1];
    const float* W1_w   = (const float*)d_in[2];
    const float* W1_b   = (const float*)d_in[3];
    const float* W2_w   = (const float*)d_in[4];
    const float* W2_b   = (const float*)d_in[5];
    const float* V_w    = (const float*)d_in[6];
    const float* V_b    = (const float*)d_in[7];
    (void)V_b;  // cancels in the shifted softmax

    float* out_weights = (float*)d_out;                 // B*S
    float* out_ctx     = (float*)d_out + BB * SS;       // B*H

    float* ws      = (float*)d_ws;
    float* ws_qq   = ws;                                 // 8192
    float* ws_wt   = ws_qq + BB * HH;                    // 131072
    float* ws_part = ws_wt + BB * SS;                    // (region reserved)
    float* ws_M    = ws_part + BB * 64 * HH;             // 1
    ushort* ws_w2  = (ushort*)(ws_M + 4);                // 65536 bf16

    static bool attr_done = false;
    if (!attr_done) {
        hipFuncSetAttribute(reinterpret_cast<const void*>(score_ctx_kernel),
                            hipFuncAttributeMaxDynamicSharedMemorySize,
                            151552);
        attr_done = true;
    }

    prep_kernel<<<dim3(256 + BB + 1), dim3(256), 0, stream>>>(
        W2_w, ws_w2, hidden, W1_w, W1_b, W2_b, V_w, ws_qq, ws_M);
    score_ctx_kernel<<<dim3(SS / 512, BB), dim3(1024), 151552, stream>>>(
        enc, ws_w2, ws_qq, V_w, ws_M, ws_wt, ws_part);
    finish_kernel<<<dim3(BB), dim3(256), 0, stream>>>(
        ws_wt, ws_part, out_weights, out_ctx);
}